// Round 1
// baseline (979.094 us; speedup 1.0000x reference)
//
#include <hip/hip_runtime.h>
#include <hip/hip_bf16.h>

// WindowMCA fused kernel for MI355X (gfx950).
// One block = one window (49 tokens, 256 ch, 8 heads x 32d), 512 threads = 8 waves,
// wave w owns head w end-to-end. All GEMMs via v_mfma_f32_16x16x32_bf16.
// S^T orientation (K·Q^T) so softmax rows are lane-local-ish and P packs cleanly.

typedef float  f32x4  __attribute__((ext_vector_type(4)));
typedef short  bf16x8 __attribute__((ext_vector_type(8)));
typedef unsigned short u16x4 __attribute__((ext_vector_type(4)));

#define LOG2E  1.4426950408889634f
#define QSCALE 0.17677669529663687f  /* 1/sqrt(32) */

__device__ __forceinline__ unsigned short f2bf(float f) {
  union { float f; unsigned u; } v; v.f = f;
  return (unsigned short)((v.u + 0x7fffu + ((v.u >> 16) & 1u)) >> 16);  // RNE
}
__device__ __forceinline__ float bf2f(unsigned short u) {
  union { unsigned u; float f; } v; v.u = ((unsigned)u) << 16; return v.f;
}
__device__ __forceinline__ unsigned pk2(float a, float b) {
  return (unsigned)f2bf(a) | ((unsigned)f2bf(b) << 16);
}

// ---------------- prep: weights -> bf16 (q_w folded with SCALE*LOG2E) ----------------
__global__ void prep_w(const float* __restrict__ qw, const float* __restrict__ kw,
                       const float* __restrict__ vw, const float* __restrict__ ow,
                       const float* __restrict__ qb, short* __restrict__ wsb,
                       float* __restrict__ qbs) {
  int t = blockIdx.x * 256 + threadIdx.x;           // 262144 = 4 * 65536
  int m = t >> 16, r = t & 65535;
  const float* s = (m == 0) ? qw : (m == 1) ? kw : (m == 2) ? vw : ow;
  float scale = (m == 0) ? (QSCALE * LOG2E) : 1.0f;
  wsb[t] = (short)f2bf(s[r] * scale);
  if (t < 256) qbs[t] = qb[t] * (QSCALE * LOG2E);
}

// ---------------- prep: cmb[wm][h][i][j] = log2e*(rpb_bias + mask), padded 64x64 ----
__global__ void prep_cmb(const float* __restrict__ mask, const float* __restrict__ rpb,
                         const int* __restrict__ relidx, short* __restrict__ cmb) {
  int t = blockIdx.x * 256 + threadIdx.x;           // 64*8*64*64 = 2097152
  int j = t & 63, i = (t >> 6) & 63, h = (t >> 12) & 7, wm = t >> 15;
  float v;
  if (j >= 49)      v = -1e38f;                     // masks padded K rows (-> exp2 = 0)
  else if (i >= 49) v = 0.f;                        // padded Q rows: finite junk, discarded
  else v = (rpb[relidx[i * 49 + j] * 8 + h] + mask[wm * 2401 + i * 49 + j]) * LOG2E;
  cmb[t] = (short)f2bf(v);
}

// ---------------- main fused kernel ----------------
// LDS: X stage [64][528B] = 33792 (reused as X2 for out-proj)
//      per-wave head region 14848B: Q[64][80B] | K[64][80B] | V^T[32][144B]
//      P[64][144B]=9216 overlays Q|K after QK^T frags are in regs.
__global__ __launch_bounds__(512) void win_attn(
    const float* __restrict__ qin, const float* __restrict__ kin, const float* __restrict__ vin,
    const float* __restrict__ kb,  const float* __restrict__ vb,  const float* __restrict__ ob,
    const short* __restrict__ wsb, const float* __restrict__ qbs,
    const short* __restrict__ cmb, float* __restrict__ out) {
  extern __shared__ char lds[];
  const int tid = threadIdx.x;
  const int w = tid >> 6, lane = tid & 63;
  const int c = lane & 15, g = lane >> 4;
  const int b = blockIdx.x, wm = b & 63;

  char* X  = lds;
  char* HB = lds + 33792 + w * 14848;
  char* QL = HB;
  char* KL = HB + 5120;
  char* VL = HB + 10240;
  char* PL = HB;                                    // P overlays Q|K (dead after frag load)

  const short* qwb = wsb;
  const short* kwb = wsb + 65536;
  const short* vwb = wsb + 131072;
  const short* owb = wsb + 196608;
  const int wbase = w * 32;                         // this wave's 32 output channels / head w

  // zero-pad X rows 49..63 once (stages only write rows 0..48)
  for (int idx = tid; idx < 495; idx += 512) {
    int row = 49 + idx / 33, ch = idx % 33;
    *reinterpret_cast<int4*>(X + row * 528 + ch * 16) = make_int4(0, 0, 0, 0);
  }

  auto stage_x = [&](const float* __restrict__ src) {
    #pragma unroll
    for (int it = 0; it < 4; ++it) {
      int chunk = tid + it * 512;
      if (chunk < 1568) {                            // 49 rows * 32 chunks of 8 floats
        int row = chunk >> 5, k0 = (chunk & 31) << 3;
        const float4* p = reinterpret_cast<const float4*>(src + row * 256 + k0);
        float4 a = p[0], d = p[1];
        int4 pk;
        pk.x = (int)pk2(a.x, a.y); pk.y = (int)pk2(a.z, a.w);
        pk.z = (int)pk2(d.x, d.y); pk.w = (int)pk2(d.z, d.w);
        *reinterpret_cast<int4*>(X + row * 528 + k0 * 2) = pk;
      }
    }
  };

  // transposed projection (Q/K): out^T[d][j] = sum_k W[d,k] X[j,k]; write [j][d] LDS
  auto proj_t = [&](const short* __restrict__ wmat, const float* __restrict__ bias, char* DST) {
    f32x4 acc[2][4] = {};
    #pragma unroll
    for (int ks = 0; ks < 8; ++ks) {
      bf16x8 af[2], bfr[4];
      #pragma unroll
      for (int mt = 0; mt < 2; ++mt)
        af[mt] = *reinterpret_cast<const bf16x8*>(wmat + (wbase + mt * 16 + c) * 256 + ks * 32 + g * 8);
      #pragma unroll
      for (int nt = 0; nt < 4; ++nt)
        bfr[nt] = *reinterpret_cast<const bf16x8*>(X + (nt * 16 + c) * 528 + ks * 64 + g * 16);
      #pragma unroll
      for (int mt = 0; mt < 2; ++mt)
        #pragma unroll
        for (int nt = 0; nt < 4; ++nt)
          acc[mt][nt] = __builtin_amdgcn_mfma_f32_16x16x32_bf16(af[mt], bfr[nt], acc[mt][nt], 0, 0, 0);
    }
    #pragma unroll
    for (int mt = 0; mt < 2; ++mt) {
      int d0 = mt * 16 + g * 4;
      float4 bi = *reinterpret_cast<const float4*>(bias + wbase + d0);
      #pragma unroll
      for (int nt = 0; nt < 4; ++nt) {
        int j = nt * 16 + c;
        f32x4 v = acc[mt][nt];
        uint2 pv; pv.x = pk2(v[0] + bi.x, v[1] + bi.y); pv.y = pk2(v[2] + bi.z, v[3] + bi.w);
        *reinterpret_cast<uint2*>(DST + j * 80 + d0 * 2) = pv;
      }
    }
  };

  // V projection (non-transposed): V[j][d]; write V^T LDS [d][j]
  auto proj_v = [&]() {
    f32x4 acc[4][2] = {};
    #pragma unroll
    for (int ks = 0; ks < 8; ++ks) {
      bf16x8 af[4], bfr[2];
      #pragma unroll
      for (int mt = 0; mt < 4; ++mt)
        af[mt] = *reinterpret_cast<const bf16x8*>(X + (mt * 16 + c) * 528 + ks * 64 + g * 16);
      #pragma unroll
      for (int nt = 0; nt < 2; ++nt)
        bfr[nt] = *reinterpret_cast<const bf16x8*>(vwb + (wbase + nt * 16 + c) * 256 + ks * 32 + g * 8);
      #pragma unroll
      for (int mt = 0; mt < 4; ++mt)
        #pragma unroll
        for (int nt = 0; nt < 2; ++nt)
          acc[mt][nt] = __builtin_amdgcn_mfma_f32_16x16x32_bf16(af[mt], bfr[nt], acc[mt][nt], 0, 0, 0);
    }
    #pragma unroll
    for (int nt = 0; nt < 2; ++nt) {
      int d = nt * 16 + c;
      float bi = vb[wbase + d];
      #pragma unroll
      for (int mt = 0; mt < 4; ++mt) {
        int j0 = mt * 16 + g * 4;
        f32x4 v = acc[mt][nt];
        uint2 pv; pv.x = pk2(v[0] + bi, v[1] + bi); pv.y = pk2(v[2] + bi, v[3] + bi);
        *reinterpret_cast<uint2*>(VL + d * 144 + j0 * 2) = pv;
      }
    }
  };

  stage_x(qin + (size_t)b * 12544); __syncthreads();
  proj_t(qwb, qbs, QL);            __syncthreads();
  stage_x(kin + (size_t)b * 12544); __syncthreads();
  proj_t(kwb, kb, KL);             __syncthreads();
  stage_x(vin + (size_t)b * 12544); __syncthreads();
  proj_v();                        __syncthreads();   // X buffer free after this

  // ---- attention, head h = w (wave-private; no barriers) ----
  bf16x8 kf[4], qf[4];
  #pragma unroll
  for (int mt = 0; mt < 4; ++mt) kf[mt] = *reinterpret_cast<const bf16x8*>(KL + (mt * 16 + c) * 80 + g * 16);
  #pragma unroll
  for (int nt = 0; nt < 4; ++nt) qf[nt] = *reinterpret_cast<const bf16x8*>(QL + (nt * 16 + c) * 80 + g * 16);

  // S^T[j][i], acc-init = cmb (bias+mask, log2e-folded)
  f32x4 s[4][4];
  const short* ch_ = cmb + ((size_t)(wm * 8 + w) * 64) * 64;
  #pragma unroll
  for (int mt = 0; mt < 4; ++mt)
    #pragma unroll
    for (int nt = 0; nt < 4; ++nt) {
      u16x4 cv = *reinterpret_cast<const u16x4*>(ch_ + (nt * 16 + c) * 64 + mt * 16 + g * 4);
      f32x4 t; t[0] = bf2f(cv[0]); t[1] = bf2f(cv[1]); t[2] = bf2f(cv[2]); t[3] = bf2f(cv[3]);
      s[mt][nt] = t;
    }
  #pragma unroll
  for (int mt = 0; mt < 4; ++mt)
    #pragma unroll
    for (int nt = 0; nt < 4; ++nt)
      s[mt][nt] = __builtin_amdgcn_mfma_f32_16x16x32_bf16(kf[mt], qf[nt], s[mt][nt], 0, 0, 0);

  // softmax over j (rows i fixed per lane: i = nt*16+c); division deferred
  float rcp[4];
  #pragma unroll
  for (int nt = 0; nt < 4; ++nt) {
    float mx = -3e38f;
    #pragma unroll
    for (int mt = 0; mt < 4; ++mt)
      #pragma unroll
      for (int r = 0; r < 4; ++r) mx = fmaxf(mx, s[mt][nt][r]);
    mx = fmaxf(mx, __shfl_xor(mx, 16));
    mx = fmaxf(mx, __shfl_xor(mx, 32));
    float sum = 0.f;
    #pragma unroll
    for (int mt = 0; mt < 4; ++mt)
      #pragma unroll
      for (int r = 0; r < 4; ++r) { float p = exp2f(s[mt][nt][r] - mx); s[mt][nt][r] = p; sum += p; }
    sum += __shfl_xor(sum, 16);
    sum += __shfl_xor(sum, 32);
    rcp[nt] = 1.f / fmaxf(sum, 1e-30f);
  }

  // write P[i][j] bf16 (overlays Q|K of this wave's head; frags already consumed)
  #pragma unroll
  for (int mt = 0; mt < 4; ++mt)
    #pragma unroll
    for (int nt = 0; nt < 4; ++nt) {
      f32x4 v = s[mt][nt];
      uint2 pv; pv.x = pk2(v[0], v[1]); pv.y = pk2(v[2], v[3]);
      *reinterpret_cast<uint2*>(PL + (nt * 16 + c) * 144 + (mt * 16 + g * 4) * 2) = pv;
    }

  // PV: x^T[d][i] = sum_j V^T[d,j] P[i,j]
  f32x4 xac[2][4] = {};
  #pragma unroll
  for (int ks = 0; ks < 2; ++ks) {
    bf16x8 va[2], pb[4];
    #pragma unroll
    for (int mt = 0; mt < 2; ++mt)
      va[mt] = *reinterpret_cast<const bf16x8*>(VL + (mt * 16 + c) * 144 + ks * 64 + g * 16);
    #pragma unroll
    for (int nt = 0; nt < 4; ++nt)
      pb[nt] = *reinterpret_cast<const bf16x8*>(PL + (nt * 16 + c) * 144 + ks * 64 + g * 16);
    #pragma unroll
    for (int mt = 0; mt < 2; ++mt)
      #pragma unroll
      for (int nt = 0; nt < 4; ++nt)
        xac[mt][nt] = __builtin_amdgcn_mfma_f32_16x16x32_bf16(va[mt], pb[nt], xac[mt][nt], 0, 0, 0);
  }

  // scale by 1/rowsum, pack, stage X2 into X buffer: X2[i][w*32+d]
  #pragma unroll
  for (int mt = 0; mt < 2; ++mt)
    #pragma unroll
    for (int nt = 0; nt < 4; ++nt) {
      f32x4 v = xac[mt][nt];
      float rc = rcp[nt];
      uint2 pv; pv.x = pk2(v[0] * rc, v[1] * rc); pv.y = pk2(v[2] * rc, v[3] * rc);
      *reinterpret_cast<uint2*>(X + (nt * 16 + c) * 528 + (wbase + mt * 16 + g * 4) * 2) = pv;
    }
  __syncthreads();

  // ---- output projection (transposed): out^T[e][i] = sum_k ow[e,k] X2[i,k] ----
  f32x4 oa[2][4] = {};
  #pragma unroll
  for (int ks = 0; ks < 8; ++ks) {
    bf16x8 af[2], bfr[4];
    #pragma unroll
    for (int mt = 0; mt < 2; ++mt)
      af[mt] = *reinterpret_cast<const bf16x8*>(owb + (wbase + mt * 16 + c) * 256 + ks * 32 + g * 8);
    #pragma unroll
    for (int nt = 0; nt < 4; ++nt)
      bfr[nt] = *reinterpret_cast<const bf16x8*>(X + (nt * 16 + c) * 528 + ks * 64 + g * 16);
    #pragma unroll
    for (int mt = 0; mt < 2; ++mt)
      #pragma unroll
      for (int nt = 0; nt < 4; ++nt)
        oa[mt][nt] = __builtin_amdgcn_mfma_f32_16x16x32_bf16(af[mt], bfr[nt], oa[mt][nt], 0, 0, 0);
  }
  #pragma unroll
  for (int mt = 0; mt < 2; ++mt) {
    int e0 = wbase + mt * 16 + g * 4;
    float4 bi = *reinterpret_cast<const float4*>(ob + e0);
    #pragma unroll
    for (int nt = 0; nt < 4; ++nt) {
      int i = nt * 16 + c;
      if (i < 49) {
        f32x4 v = oa[mt][nt];
        float4 o; o.x = v[0] + bi.x; o.y = v[1] + bi.y; o.z = v[2] + bi.z; o.w = v[3] + bi.w;
        *reinterpret_cast<float4*>(out + ((size_t)b * 49 + i) * 256 + e0) = o;
      }
    }
  }
}

extern "C" void kernel_launch(void* const* d_in, const int* in_sizes, int n_in,
                              void* d_out, int out_size, void* d_ws, size_t ws_size,
                              hipStream_t stream) {
  const float* qin  = (const float*)d_in[0];
  const float* kin  = (const float*)d_in[1];
  const float* vin  = (const float*)d_in[2];
  const float* mask = (const float*)d_in[3];
  const float* qw   = (const float*)d_in[4];
  const float* qb   = (const float*)d_in[5];
  const float* kw   = (const float*)d_in[6];
  const float* kb   = (const float*)d_in[7];
  const float* vw   = (const float*)d_in[8];
  const float* vb   = (const float*)d_in[9];
  const float* ow   = (const float*)d_in[10];
  const float* ob   = (const float*)d_in[11];
  const float* rpb  = (const float*)d_in[12];
  const int*   ridx = (const int*)d_in[13];

  short* wsb = (short*)d_ws;                          // 524288 B: q/k/v/out weights bf16
  float* qbs = (float*)((char*)d_ws + 524288);        // 1024 B: scaled q bias
  short* cmb = (short*)((char*)d_ws + 525312);        // 4 MB: [64][8][64][64] bf16

  prep_w  <<<1024, 256, 0, stream>>>(qw, kw, vw, ow, qb, wsb, qbs);
  prep_cmb<<<8192, 256, 0, stream>>>(mask, rpb, ridx, cmb);

  hipFuncSetAttribute((const void*)win_attn, hipFuncAttributeMaxDynamicSharedMemorySize, 152576);
  win_attn<<<4096, 512, 152576, stream>>>(qin, kin, vin, kb, vb, ob, wsb, qbs, cmb, (float*)d_out);
}